// Round 4
// baseline (415.028 us; speedup 1.0000x reference)
//
#include <hip/hip_runtime.h>
#include <hip/hip_cooperative_groups.h>
#include <math.h>
#include <stdint.h>

namespace cg = cooperative_groups;

#define DI __device__ __forceinline__

typedef __attribute__((ext_vector_type(8))) short bf16x8;
typedef __attribute__((ext_vector_type(4))) float f32x4;
typedef __attribute__((ext_vector_type(4))) int i32x4;

DI float elu_f(float v) { return v > 0.f ? v : expm1f(v); }

DI unsigned short f2bf(float f) {  // fp32 -> bf16 RNE
  uint32_t u = __float_as_uint(f);
  return (unsigned short)((u + 0x7FFFu + ((u >> 16) & 1u)) >> 16);
}

// ---------------- threefry2x32 (JAX, 20 rounds)
DI void threefry2x32(uint32_t k0, uint32_t k1, uint32_t& x0, uint32_t& x1) {
  uint32_t ks0 = k0, ks1 = k1, ks2 = k0 ^ k1 ^ 0x1BD11BDAu;
  x0 += ks0; x1 += ks1;
#define TFR(r) { x0 += x1; x1 = (x1 << r) | (x1 >> (32 - r)); x1 ^= x0; }
  TFR(13) TFR(15) TFR(26) TFR(6)   x0 += ks1; x1 += ks2 + 1u;
  TFR(17) TFR(29) TFR(16) TFR(24)  x0 += ks2; x1 += ks0 + 2u;
  TFR(13) TFR(15) TFR(26) TFR(6)   x0 += ks0; x1 += ks1 + 3u;
  TFR(17) TFR(29) TFR(16) TFR(24)  x0 += ks1; x1 += ks2 + 4u;
  TFR(13) TFR(15) TFR(26) TFR(6)   x0 += ks2; x1 += ks0 + 5u;
#undef TFR
}

DI float erfinv_f(float x) {  // Giles erfinv (rel err ~1e-6 << bf16 quantum)
  float w = -logf((1.0f - x) * (1.0f + x));
  float p;
  if (w < 5.0f) {
    w -= 2.5f;
    p = 2.81022636e-08f;
    p = fmaf(p, w, 3.43273939e-07f);
    p = fmaf(p, w, -3.5233877e-06f);
    p = fmaf(p, w, -4.39150654e-06f);
    p = fmaf(p, w, 0.00021858087f);
    p = fmaf(p, w, -0.00125372503f);
    p = fmaf(p, w, -0.00417768164f);
    p = fmaf(p, w, 0.246640727f);
    p = fmaf(p, w, 1.50140941f);
  } else {
    w = sqrtf(w) - 3.0f;
    p = -0.000200214257f;
    p = fmaf(p, w, 0.000100950558f);
    p = fmaf(p, w, 0.00134934322f);
    p = fmaf(p, w, -0.00367342844f);
    p = fmaf(p, w, 0.00573950773f);
    p = fmaf(p, w, -0.0076224613f);
    p = fmaf(p, w, 0.00943887047f);
    p = fmaf(p, w, 1.00167406f);
    p = fmaf(p, w, 2.83297682f);
  }
  return p * x;
}

struct MegaArgs {
  const float *x, *c;
  const float *fc1w, *fc1b, *fc2w, *fc2b, *muw, *mub, *lvw, *lvb;
  const float *g0w, *g0b, *g1w, *g1b, *g2w, *g2b;
  const float *w0, *b0, *w1, *b1, *w2, *b2;
  unsigned short *Ax, *Axh, *Axh2, *A0, *A1, *A2;
  unsigned short *fc1t, *fc2t, *mlvt, *g0t, *g1t, *w0b, *w1b, *w2b;
  float *cf, *outY, *outMu, *outLv;
};

// =====================================================================
// Unified 32x64 GEMM tile: A full-K LDS, W wave-private 3-deep buffered,
// no inner barriers. OUT: 0=bf16->Cb  1=f32->outY  2=raw->LDS mlvS  3=bf16->LDS Cb
template <int KT, int NE, bool ELU, int OUT, bool APRE>
DI void gemm_tile(unsigned char* SM, int tid,
                  const unsigned short* __restrict__ A, int m0, int n0,
                  const unsigned short* __restrict__ Wt, int N,
                  const float* __restrict__ bias, const float* __restrict__ cfp,
                  unsigned short* __restrict__ Cb, int ldcb, int cb_off,
                  float* __restrict__ Cf) {
  constexpr int Kp = KT * 32, LKA = Kp + 8, CPR = Kp / 8;
  constexpr int NCH = (KT + 1) / 2, total = NE * NCH;
  constexpr int wOff = 32 * LKA * 2;            // As size (16B-mult)
  constexpr int biasOff = wOff + 27648;          // Wp: 4 waves * 3 bufs * 16*72*2B
  constexpr int cfOff = biasOff + NE * 64 * 4;
  unsigned short* As = (unsigned short*)SM;
  unsigned short* Wp = (unsigned short*)(SM + wOff);
  float* bias_s = (float*)(SM + biasOff);
  float* cfs = (float*)(SM + cfOff);
  const int lane = tid & 63, wid = tid >> 6, q = lane >> 4, l16 = lane & 15;
  const int cl = wid * 16 + l16, gc = n0 + cl;
  unsigned short* myW = Wp + wid * 3456;

  __syncthreads();  // protect LDS from previous phase/tile still reading

  auto loadW = [&](int g, i32x4 (&r)[2]) {
    int e = (NE > 1) ? (g / NCH) : 0;
    int c2 = (NE > 1) ? (g % NCH) : g;
#pragma unroll
    for (int s = 0; s < 2; s++) {
      int idx = lane + s * 64, row = idx >> 3, ch = idx & 7;
      int gn = n0 + wid * 16 + row, kk = c2 * 64 + ch * 8;
      if (gn < N && kk < Kp)
        r[s] = *(const i32x4*)(Wt + ((size_t)e * N + gn) * Kp + kk);
      else { r[s][0] = 0; r[s][1] = 0; r[s][2] = 0; r[s][3] = 0; }
    }
  };
  auto storeW = [&](int g, i32x4 (&r)[2]) {
    int buf = g % 3;
#pragma unroll
    for (int s = 0; s < 2; s++) {
      int idx = lane + s * 64, row = idx >> 3, ch = idx & 7;
      *(i32x4*)(myW + (buf * 16 + row) * 72 + ch * 8) = r[s];
    }
  };

  i32x4 rg0[2], rg1[2];
  loadW(0, rg0);
  if (1 < total) loadW(1, rg1);
  if (!APRE) {
    for (int idx = tid; idx < 32 * CPR; idx += 256) {
      int row = idx / CPR, ch = idx % CPR;
      *(i32x4*)(As + row * LKA + ch * 8) =
          *(const i32x4*)(A + (size_t)(m0 + row) * Kp + ch * 8);
    }
  }
  if (bias) {
    for (int idx = tid; idx < NE * 64; idx += 256) {
      int e = idx >> 6, col = idx & 63;
      bias_s[idx] = (n0 + col < N) ? bias[(size_t)e * N + n0 + col] : 0.f;
    }
  }
  if (NE > 1) cfs[tid] = cfp[(size_t)(m0 + (tid >> 3)) * 8 + (tid & 7)];
  storeW(0, rg0);
  if (2 < total) loadW(2, rg0);
  __syncthreads();

  f32x4 acc[2] = {{0,0,0,0},{0,0,0,0}}, accF[2] = {{0,0,0,0},{0,0,0,0}};
  auto step = [&](int g, i32x4 (&rr)[2]) {
    int c2 = (NE > 1) ? (g % NCH) : g;
    int buf = g % 3;
#pragma unroll
    for (int tl = 0; tl < 2; tl++) {
      int tau = c2 * 2 + tl;
      if (tau >= KT) break;
      bf16x8 bv = *(const bf16x8*)(myW + (buf * 16 + l16) * 72 + tl * 32 + q * 8);
#pragma unroll
      for (int mi = 0; mi < 2; mi++) {
        bf16x8 av = *(const bf16x8*)(As + (mi * 16 + l16) * LKA + tau * 32 + q * 8);
        acc[mi] = __builtin_amdgcn_mfma_f32_16x16x32_bf16(av, bv, acc[mi], 0, 0, 0);
      }
    }
    if (g + 1 < total) storeW(g + 1, rr);
    if (g + 3 < total) loadW(g + 3, rr);
    if (NE > 1 && c2 == NCH - 1) {  // expert boundary: exact fp32 fold
      int e = g / NCH;
      float bv2 = bias_s[e * 64 + cl];
#pragma unroll
      for (int mi = 0; mi < 2; mi++)
#pragma unroll
        for (int r = 0; r < 4; r++) {
          float ce = cfs[(mi * 16 + q * 4 + r) * 8 + e];
          accF[mi][r] += ce * (acc[mi][r] + bv2);
          acc[mi][r] = 0.f;
        }
    }
  };
  for (int g = 0; g < total; g += 2) {
    step(g, rg1);
    if (g + 1 < total) step(g + 1, rg0);
  }

  if (OUT == 2) {
    __syncthreads();  // As dead; overlay mlvS
    float* mlvS = (float*)SM;
#pragma unroll
    for (int mi = 0; mi < 2; mi++)
#pragma unroll
      for (int r = 0; r < 4; r++)
        mlvS[(mi * 16 + q * 4 + r) * 65 + cl] = acc[mi][r];
  } else if (OUT == 3) {
#pragma unroll
    for (int mi = 0; mi < 2; mi++)
#pragma unroll
      for (int r = 0; r < 4; r++) {
        float v = acc[mi][r] + bias_s[cl];
        Cb[(mi * 16 + q * 4 + r) * 72 + cl] = f2bf(elu_f(v));
      }
  } else {
    if (gc < N) {
#pragma unroll
      for (int mi = 0; mi < 2; mi++)
#pragma unroll
        for (int r = 0; r < 4; r++) {
          int row = m0 + mi * 16 + q * 4 + r;
          float v = (NE > 1) ? accF[mi][r] : (acc[mi][r] + bias_s[cl]);
          if (ELU) v = elu_f(v);
          if (OUT == 0) Cb[(size_t)row * ldcb + cb_off + gc] = f2bf(v);
          else Cf[(size_t)row * 267 + gc] = v;
        }
    }
  }
}

// =====================================================================
// Phase bodies
DI void phase_prep(const MegaArgs& a, unsigned char* SM, int tid, int bid, int nblk) {
  for (int bb = bid; bb < 1673; bb += nblk) {
    if (bb < 512) {
      for (int rr = 0; rr < 4; rr++) {
        int b = bb * 4 + rr;
        const float* xr = a.x + (size_t)b * 267;
        const float* cr = a.c + (size_t)b * 267;
        unsigned short* axr = a.Ax + (size_t)b * 544;
        for (int k = tid; k < 544; k += 256) {
          float v = (k < 267) ? xr[k] : ((k < 534) ? cr[k - 267] : 0.f);
          axr[k] = f2bf(v);
        }
        unsigned short* ahr = a.Axh + (size_t)b * 544;
        unsigned short* ah2 = a.Axh2 + (size_t)b * 544;
        for (int k = tid; k < 267; k += 256) { unsigned short v = f2bf(xr[k]); ahr[k] = v; ah2[k] = v; }
        for (int k = 523 + tid; k < 544; k += 256) { ahr[k] = 0; ah2[k] = 0; }
        unsigned short* a0r = a.A0 + (size_t)b * 320;
        for (int k = tid; k < 288; k += 256)
          a0r[32 + k] = (k < 267) ? f2bf(cr[k]) : (unsigned short)0;
      }
    } else if (bb < 1152) {
      int r = bb - 512;
      const float* src; unsigned short* dst; int Ks, Kp2;
      if (r < 256)      { src = a.fc1w + (size_t)r * 534; dst = a.fc1t + (size_t)r * 544; Ks = 534; Kp2 = 544; }
      else if (r < 512) { int n = r - 256; src = a.fc2w + (size_t)n * 523; dst = a.fc2t + (size_t)n * 544; Ks = 523; Kp2 = 544; }
      else if (r < 576) { int n = r - 512; src = (n < 32) ? (a.muw + (size_t)n * 523) : (a.lvw + (size_t)(n - 32) * 523);
                          dst = a.mlvt + (size_t)n * 544; Ks = 523; Kp2 = 544; }
      else              { int n = r - 576; src = a.g0w + (size_t)n * 299; dst = a.g0t + (size_t)n * 320; Ks = 299; Kp2 = 320; }
      for (int k = tid; k < Kp2; k += 256) dst[k] = (k < Ks) ? f2bf(src[k]) : (unsigned short)0;
    } else if (bb == 1152) {
      for (int k = tid; k < 4096; k += 256) a.g1t[k] = f2bf(a.g1w[k]);
    } else {
      int t = bb - 1153;
      const float* W; unsigned short* D; int K, N2, Kp2, ldW, e, kt, nt;
      if (t < 160)      { e = t / 20;  int lt = t % 20;  kt = lt / 4; nt = lt % 4; W = a.w0; D = a.w0b; K = 299; N2 = 256; Kp2 = 320; ldW = 256; }
      else if (t < 320) { int u = t - 160; e = u / 20; int lt = u % 20; kt = lt / 4; nt = lt % 4; W = a.w1; D = a.w1b; K = 288; N2 = 256; Kp2 = 288; ldW = 256; }
      else              { int u = t - 320; e = u / 25; int lt = u % 25; kt = lt / 5; nt = lt % 5; W = a.w2; D = a.w2b; K = 288; N2 = 267; Kp2 = 288; ldW = 267; }
      unsigned short (*T)[72] = (unsigned short (*)[72])SM;
      const int k0 = kt * 64, n0 = nt * 64;
      const float* We = W + (size_t)e * K * ldW;
      const int jj = tid & 63, ii0 = tid >> 6;
      __syncthreads();
#pragma unroll
      for (int p = 0; p < 16; p++) {
        int i = ii0 + p * 4;
        int gk = k0 + i, gn = n0 + jj;
        float v = (gk < K && gn < N2) ? We[(size_t)gk * ldW + gn] : 0.f;
        T[jj][i] = f2bf(v);
      }
      __syncthreads();
      int j = tid >> 2, chb = tid & 3;
      int gn = n0 + j;
      if (gn < N2) {
        unsigned short* drow = D + ((size_t)e * N2 + gn) * Kp2 + k0;
#pragma unroll
        for (int s = 0; s < 2; s++) {
          int ch = chb + s * 4;
          if (k0 + ch * 8 < Kp2) {
            i32x4 v = *(i32x4*)(&T[j][ch * 8]);
            *(i32x4*)(drow + ch * 8) = v;
          }
        }
      }
      __syncthreads();
    }
  }
}

DI void phase_fc1(const MegaArgs& a, unsigned char* SM, int tid, int b) {
  gemm_tile<17, 1, true, 0, false>(SM, tid, a.Ax, (b >> 2) * 32, (b & 3) * 64,
                                   a.fc1t, 256, a.fc1b, nullptr, a.Axh, 544, 267, nullptr);
}
DI void phase_fc2(const MegaArgs& a, unsigned char* SM, int tid, int b) {
  gemm_tile<17, 1, true, 0, false>(SM, tid, a.Axh, (b >> 2) * 32, (b & 3) * 64,
                                   a.fc2t, 256, a.fc2b, nullptr, a.Axh2, 544, 267, nullptr);
}

// mu/lv GEMM + z + full gate stack, per 32-row tile (bid < 64)
DI void phase_mulv_gate(const MegaArgs& a, unsigned char* SM, int tid, int bid) {
  const int m0 = bid * 32;
  gemm_tile<17, 1, false, 2, false>(SM, tid, a.Axh2, m0, 0, a.mlvt, 64,
                                    nullptr, nullptr, nullptr, 0, 0, nullptr);
  __syncthreads();
  float* mlvS = (float*)SM;
  const int m = tid >> 3, j0 = (tid & 7) * 4;
  const int R = m0 + m;
  unsigned short zb[4];
#pragma unroll
  for (int jj = 0; jj < 4; jj++) {
    int j = j0 + jj;
    float mu = mlvS[m * 65 + j] + a.mub[j];
    float lvv = mlvS[m * 65 + j + 32] + a.lvb[j];
    uint32_t x0 = 0u, x1 = (uint32_t)(R * 32 + j);
    threefry2x32(0u, 42u, x0, x1);
    uint32_t bits = x0 ^ x1;
    float f = __uint_as_float((bits >> 9) | 0x3F800000u) - 1.0f;
    const float lo = -0.99999994039535522461f;
    float u = fmaf(f, 2.0f, lo);
    u = fmaxf(u, lo);
    float eps = 1.41421356237f * erfinv_f(u);
    float z = fmaf(eps, expf(0.5f * lvv), mu);
    a.outMu[(size_t)R * 32 + j] = mu;
    a.outLv[(size_t)R * 32 + j] = lvv;
    zb[jj] = f2bf(z);
    a.A0[(size_t)R * 320 + j] = zb[jj];
    a.A1[(size_t)R * 288 + j] = zb[jj];
    a.A2[(size_t)R * 288 + j] = zb[jj];
  }
  __syncthreads();  // mlvS reads done
  unsigned short* A0p = (unsigned short*)SM;  // [32][328]
  for (int idx = tid; idx < 32 * 36; idx += 256) {
    int row = idx / 36, ch = 4 + idx % 36;
    *(i32x4*)(A0p + row * 328 + ch * 8) =
        *(const i32x4*)(a.A0 + (size_t)(m0 + row) * 320 + ch * 8);
  }
  if (tid < 32) { i32x4 zz; zz[0]=0; zz[1]=0; zz[2]=0; zz[3]=0; *(i32x4*)(A0p + tid * 328 + 320) = zz; }
#pragma unroll
  for (int jj = 0; jj < 4; jj++) A0p[m * 328 + j0 + jj] = zb[jj];
  // g0: A prestaged in LDS (sync inside gemm_tile covers the writes above)
  gemm_tile<10, 1, false, 3, true>(SM, tid, nullptr, 0, 0, a.g0t, 64, a.g0b, nullptr,
                                   (unsigned short*)(SM + 49664), 0, 0, nullptr);
  __syncthreads();
  unsigned short* gaB = (unsigned short*)(SM + 49664);  // [32][72]
  unsigned short* g1B = (unsigned short*)(SM + 54272);  // [64][72]
  for (int idx = tid; idx < 512; idx += 256) {
    int row = idx >> 3, ch = idx & 7;
    *(i32x4*)(g1B + row * 72 + ch * 8) = *(const i32x4*)(a.g1t + (size_t)row * 64 + ch * 8);
  }
  __syncthreads();
  const int lane = tid & 63, wid = tid >> 6, q = lane >> 4, l16 = lane & 15;
  const int cl = wid * 16 + l16;
  f32x4 acc2[2] = {{0,0,0,0},{0,0,0,0}};
#pragma unroll
  for (int tau = 0; tau < 2; tau++) {
    bf16x8 bv = *(const bf16x8*)(g1B + (size_t)cl * 72 + tau * 32 + q * 8);
#pragma unroll
    for (int mi = 0; mi < 2; mi++) {
      bf16x8 av = *(const bf16x8*)(gaB + (mi * 16 + l16) * 72 + tau * 32 + q * 8);
      acc2[mi] = __builtin_amdgcn_mfma_f32_16x16x32_bf16(av, bv, acc2[mi], 0, 0, 0);
    }
  }
  float* gB = (float*)SM;  // [32][65] — A0p dead
  {
    float b1c = a.g1b[cl];
#pragma unroll
    for (int mi = 0; mi < 2; mi++)
#pragma unroll
      for (int r = 0; r < 4; r++)
        gB[(mi * 16 + q * 4 + r) * 65 + cl] = elu_f(acc2[mi][r] + b1c);
  }
  __syncthreads();
  float* lg = (float*)(SM + 8448);  // [32][8]
  {
    int r = tid >> 3, e = tid & 7;
    float acc3 = a.g2b[e];
    for (int k = 0; k < 64; k++) acc3 = fmaf(gB[r * 65 + k], a.g2w[e * 64 + k], acc3);
    lg[r * 8 + e] = acc3;
  }
  __syncthreads();
  if (tid < 32) {
    float mx = lg[tid * 8];
#pragma unroll
    for (int e2 = 1; e2 < 8; e2++) mx = fmaxf(mx, lg[tid * 8 + e2]);
    float s = 0.f, ex[8];
#pragma unroll
    for (int e2 = 0; e2 < 8; e2++) { ex[e2] = expf(lg[tid * 8 + e2] - mx); s += ex[e2]; }
    float inv = 1.f / s;
#pragma unroll
    for (int e2 = 0; e2 < 8; e2++) a.cf[(size_t)(m0 + tid) * 8 + e2] = ex[e2] * inv;
  }
}

DI void phase_moe0(const MegaArgs& a, unsigned char* SM, int tid, int b) {
  gemm_tile<10, 8, true, 0, false>(SM, tid, a.A0, (b >> 2) * 32, (b & 3) * 64,
                                   a.w0b, 256, a.b0, a.cf, a.A1, 288, 32, nullptr);
}
DI void phase_moe1(const MegaArgs& a, unsigned char* SM, int tid, int b) {
  gemm_tile<9, 8, true, 0, false>(SM, tid, a.A1, (b >> 2) * 32, (b & 3) * 64,
                                  a.w1b, 256, a.b1, a.cf, a.A2, 288, 32, nullptr);
}
DI void phase_moe2(const MegaArgs& a, unsigned char* SM, int tid, int bid, int nblk) {
  for (int t = bid; t < 320; t += nblk)
    gemm_tile<9, 8, false, 1, false>(SM, tid, a.A2, (t / 5) * 32, (t % 5) * 64,
                                     a.w2b, 267, a.b2, a.cf, nullptr, 0, 0, a.outY);
}

// =====================================================================
__global__ __launch_bounds__(256, 1) void mega_kernel(MegaArgs a) {
  __shared__ __align__(16) unsigned char SM[63488];
  const int tid = threadIdx.x, bid = blockIdx.x, nblk = gridDim.x;
  cg::grid_group grid = cg::this_grid();
  phase_prep(a, SM, tid, bid, nblk);
  grid.sync();
  phase_fc1(a, SM, tid, bid);
  grid.sync();
  phase_fc2(a, SM, tid, bid);
  grid.sync();
  if (bid < 64) phase_mulv_gate(a, SM, tid, bid);
  grid.sync();
  phase_moe0(a, SM, tid, bid);
  grid.sync();
  phase_moe1(a, SM, tid, bid);
  grid.sync();
  phase_moe2(a, SM, tid, bid, nblk);
}

// -------- fallback (non-cooperative) phase kernels --------
__global__ __launch_bounds__(256, 1) void k_prep(MegaArgs a) {
  __shared__ __align__(16) unsigned char SM[63488];
  phase_prep(a, SM, threadIdx.x, blockIdx.x, gridDim.x);
}
__global__ __launch_bounds__(256, 1) void k_fc1(MegaArgs a) {
  __shared__ __align__(16) unsigned char SM[63488];
  phase_fc1(a, SM, threadIdx.x, blockIdx.x);
}
__global__ __launch_bounds__(256, 1) void k_fc2(MegaArgs a) {
  __shared__ __align__(16) unsigned char SM[63488];
  phase_fc2(a, SM, threadIdx.x, blockIdx.x);
}
__global__ __launch_bounds__(256, 1) void k_p3(MegaArgs a) {
  __shared__ __align__(16) unsigned char SM[63488];
  phase_mulv_gate(a, SM, threadIdx.x, blockIdx.x);
}
__global__ __launch_bounds__(256, 1) void k_moe0(MegaArgs a) {
  __shared__ __align__(16) unsigned char SM[63488];
  phase_moe0(a, SM, threadIdx.x, blockIdx.x);
}
__global__ __launch_bounds__(256, 1) void k_moe1(MegaArgs a) {
  __shared__ __align__(16) unsigned char SM[63488];
  phase_moe1(a, SM, threadIdx.x, blockIdx.x);
}
__global__ __launch_bounds__(256, 1) void k_moe2(MegaArgs a) {
  __shared__ __align__(16) unsigned char SM[63488];
  phase_moe2(a, SM, threadIdx.x, blockIdx.x, gridDim.x);
}

// =====================================================================
extern "C" void kernel_launch(void* const* d_in, const int* in_sizes, int n_in,
                              void* d_out, int out_size, void* d_ws, size_t ws_size,
                              hipStream_t stream) {
  (void)in_sizes; (void)n_in; (void)out_size; (void)ws_size;
  float* out = (float*)d_out;
  float* ws = (float*)d_ws;

  MegaArgs a;
  a.x    = (const float*)d_in[0];
  a.c    = (const float*)d_in[1];
  a.fc1w = (const float*)d_in[2];  a.fc1b = (const float*)d_in[3];
  a.fc2w = (const float*)d_in[4];  a.fc2b = (const float*)d_in[5];
  a.muw  = (const float*)d_in[6];  a.mub  = (const float*)d_in[7];
  a.lvw  = (const float*)d_in[8];  a.lvb  = (const float*)d_in[9];
  a.g0w  = (const float*)d_in[10]; a.g0b  = (const float*)d_in[11];
  a.g1w  = (const float*)d_in[12]; a.g1b  = (const float*)d_in[13];
  a.g2w  = (const float*)d_in[14]; a.g2b  = (const float*)d_in[15];
  a.w0   = (const float*)d_in[16]; a.b0   = (const float*)d_in[17];
  a.w1   = (const float*)d_in[18]; a.b1   = (const float*)d_in[19];
  a.w2   = (const float*)d_in[20]; a.b2   = (const float*)d_in[21];

  a.outY  = out;
  a.outMu = out + 2048 * 267;
  a.outLv = a.outMu + 2048 * 32;

  a.Ax   = (unsigned short*)(ws);
  a.Axh  = (unsigned short*)(ws + 557056);
  a.Axh2 = (unsigned short*)(ws + 1114112);
  a.A0   = (unsigned short*)(ws + 1671168);
  a.A1   = (unsigned short*)(ws + 1998848);
  a.A2   = (unsigned short*)(ws + 2293760);
  a.fc1t = (unsigned short*)(ws + 2588672);
  a.fc2t = (unsigned short*)(ws + 2658304);
  a.mlvt = (unsigned short*)(ws + 2727936);
  a.g0t  = (unsigned short*)(ws + 2745344);
  a.g1t  = (unsigned short*)(ws + 2755584);
  a.w0b  = (unsigned short*)(ws + 2757632);
  a.w1b  = (unsigned short*)(ws + 3085312);
  a.w2b  = (unsigned short*)(ws + 3380224);
  a.cf   = ws + 3687808;

  void* kp[] = { (void*)&a };
  hipError_t err = hipLaunchCooperativeKernel((const void*)mega_kernel,
                                              dim3(256), dim3(256), kp, 0, stream);
  if (err != hipSuccess) {
    // fallback: same phase bodies as separate dispatches
    dim3 blk(256);
    k_prep<<<256, blk, 0, stream>>>(a);
    k_fc1<<<256, blk, 0, stream>>>(a);
    k_fc2<<<256, blk, 0, stream>>>(a);
    k_p3<<<64, blk, 0, stream>>>(a);
    k_moe0<<<256, blk, 0, stream>>>(a);
    k_moe1<<<256, blk, 0, stream>>>(a);
    k_moe2<<<256, blk, 0, stream>>>(a);
  }
}

// Round 5
// 204.420 us; speedup vs baseline: 2.0303x; 2.0303x over previous
//
#include <hip/hip_runtime.h>
#include <math.h>
#include <stdint.h>

#define DI __device__ __forceinline__

typedef __attribute__((ext_vector_type(8))) short bf16x8;
typedef __attribute__((ext_vector_type(4))) float f32x4;
typedef __attribute__((ext_vector_type(4))) int i32x4;

DI float elu_f(float v) { return v > 0.f ? v : expm1f(v); }

DI unsigned short f2bf(float f) {  // fp32 -> bf16 RNE
  uint32_t u = __float_as_uint(f);
  return (unsigned short)((u + 0x7FFFu + ((u >> 16) & 1u)) >> 16);
}

// ---------------- threefry2x32 (JAX, 20 rounds)
DI void threefry2x32(uint32_t k0, uint32_t k1, uint32_t& x0, uint32_t& x1) {
  uint32_t ks0 = k0, ks1 = k1, ks2 = k0 ^ k1 ^ 0x1BD11BDAu;
  x0 += ks0; x1 += ks1;
#define TFR(r) { x0 += x1; x1 = (x1 << r) | (x1 >> (32 - r)); x1 ^= x0; }
  TFR(13) TFR(15) TFR(26) TFR(6)   x0 += ks1; x1 += ks2 + 1u;
  TFR(17) TFR(29) TFR(16) TFR(24)  x0 += ks2; x1 += ks0 + 2u;
  TFR(13) TFR(15) TFR(26) TFR(6)   x0 += ks0; x1 += ks1 + 3u;
  TFR(17) TFR(29) TFR(16) TFR(24)  x0 += ks1; x1 += ks2 + 4u;
  TFR(13) TFR(15) TFR(26) TFR(6)   x0 += ks2; x1 += ks0 + 5u;
#undef TFR
}

DI float erfinv_f(float x) {  // Giles erfinv (rel err ~1e-6 << bf16 quantum)
  float w = -logf((1.0f - x) * (1.0f + x));
  float p;
  if (w < 5.0f) {
    w -= 2.5f;
    p = 2.81022636e-08f;
    p = fmaf(p, w, 3.43273939e-07f);
    p = fmaf(p, w, -3.5233877e-06f);
    p = fmaf(p, w, -4.39150654e-06f);
    p = fmaf(p, w, 0.00021858087f);
    p = fmaf(p, w, -0.00125372503f);
    p = fmaf(p, w, -0.00417768164f);
    p = fmaf(p, w, 0.246640727f);
    p = fmaf(p, w, 1.50140941f);
  } else {
    w = sqrtf(w) - 3.0f;
    p = -0.000200214257f;
    p = fmaf(p, w, 0.000100950558f);
    p = fmaf(p, w, 0.00134934322f);
    p = fmaf(p, w, -0.00367342844f);
    p = fmaf(p, w, 0.00573950773f);
    p = fmaf(p, w, -0.0076224613f);
    p = fmaf(p, w, 0.00943887047f);
    p = fmaf(p, w, 1.00167406f);
    p = fmaf(p, w, 2.83297682f);
  }
  return p * x;
}

struct MegaArgs {
  const float *x, *c;
  const float *fc1w, *fc1b, *fc2w, *fc2b, *muw, *mub, *lvw, *lvb;
  const float *g0w, *g0b, *g1w, *g1b, *g2w, *g2b;
  const float *w0, *b0, *w1, *b1, *w2, *b2;
  unsigned short *Ax, *Axh, *Axh2, *A0, *A1, *A2;
  unsigned short *fc1t, *fc2t, *mlvt, *g0t, *g1t, *w0b, *w1b, *w2b;
  float *cf, *outY, *outMu, *outLv;
};

// =====================================================================
// pipe_gemm: 32-row x 64-col tile, 4 waves (each 32r x 16c).
// W fragments stream GLOBAL -> register ring (depth 8) -> MFMA. No LDS
// round-trip for W, no inner barriers, deep vmcnt pipeline (AITER-style).
// A panel staged once in LDS; for MoE (NE=8) A-frags cached in VGPRs and
// reused across all 8 experts. Expert mixing folded in exact fp32.
template <int KT, int NE, bool ELU, bool OUTF32, bool AREG>
__global__ __launch_bounds__(256, 1)
void pipe_gemm(const unsigned short* __restrict__ A,         // [2048][Kp]
               const unsigned short* __restrict__ Wt, int N, // [NE][N][Kp]
               const float* __restrict__ bias,               // [NE][N]
               const float* __restrict__ cfp,                // [2048][8] | null
               unsigned short* __restrict__ Cb, int ldcb, int cb_off,
               float* __restrict__ Cf) {
  constexpr int Kp = KT * 32, LKA = Kp + 8, CPR = Kp / 8;
  constexpr int D = 8, TT = NE * KT;
  __shared__ unsigned short As[32 * LKA];
  __shared__ float bias_s[NE * 64];
  __shared__ float cfs[256];
  const int tid = threadIdx.x, lane = tid & 63, wid = tid >> 6;
  const int q = lane >> 4, l16 = lane & 15;
  const int m0 = blockIdx.x * 32, n0 = blockIdx.y * 64;
  const int cl = wid * 16 + l16;
  const int gc = n0 + cl;
  const int wrow = (gc < N) ? gc : (N - 1);  // clamp: OOB lanes load junk, never stored

  // lane's W base: row wrow, k-offset q*8 (B-frag = 16 contiguous bytes)
  const unsigned short* wlane = Wt + (size_t)wrow * Kp + q * 8;

  // W prologue: fill the ring (loads in flight across LDS staging below)
  bf16x8 ring[D];
#pragma unroll
  for (int g = 0; g < D; g++) {
    if (g < TT) {
      constexpr int KTc = KT;
      int e = g / KTc, c = g % KTc;
      ring[g] = *(const bf16x8*)(wlane + (size_t)e * N * Kp + c * 32);
    }
  }
  // stage A panel (coalesced 16B chunks)
  for (int idx = tid; idx < 32 * CPR; idx += 256) {
    int row = idx / CPR, ch = idx % CPR;
    *(i32x4*)(As + row * LKA + ch * 8) =
        *(const i32x4*)(A + (size_t)(m0 + row) * Kp + ch * 8);
  }
  for (int idx = tid; idx < NE * 64; idx += 256) {
    int e = idx >> 6, col = idx & 63;
    bias_s[idx] = (n0 + col < N) ? bias[(size_t)e * N + n0 + col] : 0.f;
  }
  if (NE > 1) cfs[tid] = cfp[(size_t)(m0 + (tid >> 3)) * 8 + (tid & 7)];
  __syncthreads();

  // A-frag register cache (MoE: reused by all 8 experts)
  bf16x8 areg[AREG ? 2 * KT : 1];
  if (AREG) {
#pragma unroll
    for (int c = 0; c < KT; c++)
#pragma unroll
      for (int mi = 0; mi < 2; mi++)
        areg[c * 2 + mi] = *(const bf16x8*)(As + (mi * 16 + l16) * LKA + c * 32 + q * 8);
  }

  f32x4 acc[2] = {{0, 0, 0, 0}, {0, 0, 0, 0}};
  f32x4 accF[2] = {{0, 0, 0, 0}, {0, 0, 0, 0}};
#pragma unroll
  for (int g = 0; g < TT; g++) {
    const int e = g / KT, c = g % KT;
    bf16x8 bv = ring[g % D];
#pragma unroll
    for (int mi = 0; mi < 2; mi++) {
      bf16x8 av = AREG ? areg[c * 2 + mi]
                       : *(const bf16x8*)(As + (mi * 16 + l16) * LKA + c * 32 + q * 8);
      acc[mi] = __builtin_amdgcn_mfma_f32_16x16x32_bf16(av, bv, acc[mi], 0, 0, 0);
    }
    if (g + D < TT) {  // refill ring slot (8 loads in flight)
      int e2 = (g + D) / KT, c2 = (g + D) % KT;
      ring[g % D] = *(const bf16x8*)(wlane + (size_t)e2 * N * Kp + c2 * 32);
    }
    if (NE > 1 && c == KT - 1) {  // expert boundary: exact fp32 fold
      float bv2 = bias_s[e * 64 + cl];
#pragma unroll
      for (int mi = 0; mi < 2; mi++)
#pragma unroll
        for (int r = 0; r < 4; r++) {
          float ce = cfs[(mi * 16 + q * 4 + r) * 8 + e];
          accF[mi][r] += ce * (acc[mi][r] + bv2);
          acc[mi][r] = 0.f;
        }
    }
  }

  if (gc < N) {
#pragma unroll
    for (int mi = 0; mi < 2; mi++)
#pragma unroll
      for (int r = 0; r < 4; r++) {
        int row = m0 + mi * 16 + q * 4 + r;
        float v = (NE > 1) ? accF[mi][r] : (acc[mi][r] + bias_s[cl]);
        if (ELU) v = elu_f(v);
        if (OUTF32) Cf[(size_t)row * 267 + gc] = v;
        else Cb[(size_t)row * ldcb + cb_off + gc] = f2bf(v);
      }
  }
}

// =====================================================================
// old-style gemm_tile (kept ONLY for the small N=64 mulv/gate phases)
template <int KT, int NE, bool ELU, int OUT, bool APRE>
DI void gemm_tile(unsigned char* SM, int tid,
                  const unsigned short* __restrict__ A, int m0, int n0,
                  const unsigned short* __restrict__ Wt, int N,
                  const float* __restrict__ bias, const float* __restrict__ cfp,
                  unsigned short* __restrict__ Cb, int ldcb, int cb_off,
                  float* __restrict__ Cf) {
  constexpr int Kp = KT * 32, LKA = Kp + 8, CPR = Kp / 8;
  constexpr int NCH = (KT + 1) / 2, total = NE * NCH;
  constexpr int wOff = 32 * LKA * 2;
  constexpr int biasOff = wOff + 27648;
  unsigned short* As = (unsigned short*)SM;
  unsigned short* Wp = (unsigned short*)(SM + wOff);
  float* bias_s = (float*)(SM + biasOff);
  const int lane = tid & 63, wid = tid >> 6, q = lane >> 4, l16 = lane & 15;
  const int cl = wid * 16 + l16;
  unsigned short* myW = Wp + wid * 3456;

  __syncthreads();

  auto loadW = [&](int g, i32x4 (&r)[2]) {
    int c2 = g;
#pragma unroll
    for (int s = 0; s < 2; s++) {
      int idx = lane + s * 64, row = idx >> 3, ch = idx & 7;
      int gn = n0 + wid * 16 + row, kk = c2 * 64 + ch * 8;
      if (gn < N && kk < Kp)
        r[s] = *(const i32x4*)(Wt + (size_t)gn * Kp + kk);
      else { r[s][0] = 0; r[s][1] = 0; r[s][2] = 0; r[s][3] = 0; }
    }
  };
  auto storeW = [&](int g, i32x4 (&r)[2]) {
    int buf = g % 3;
#pragma unroll
    for (int s = 0; s < 2; s++) {
      int idx = lane + s * 64, row = idx >> 3, ch = idx & 7;
      *(i32x4*)(myW + (buf * 16 + row) * 72 + ch * 8) = r[s];
    }
  };

  i32x4 rg0[2], rg1[2];
  loadW(0, rg0);
  if (1 < total) loadW(1, rg1);
  if (!APRE) {
    for (int idx = tid; idx < 32 * CPR; idx += 256) {
      int row = idx / CPR, ch = idx % CPR;
      *(i32x4*)(As + row * LKA + ch * 8) =
          *(const i32x4*)(A + (size_t)(m0 + row) * Kp + ch * 8);
    }
  }
  if (bias) {
    for (int idx = tid; idx < 64; idx += 256) {
      int col = idx & 63;
      bias_s[idx] = (n0 + col < N) ? bias[n0 + col] : 0.f;
    }
  }
  storeW(0, rg0);
  if (2 < total) loadW(2, rg0);
  __syncthreads();

  f32x4 acc[2] = {{0,0,0,0},{0,0,0,0}};
  auto step = [&](int g, i32x4 (&rr)[2]) {
    int c2 = g;
    int buf = g % 3;
#pragma unroll
    for (int tl = 0; tl < 2; tl++) {
      int tau = c2 * 2 + tl;
      if (tau >= KT) break;
      bf16x8 bv = *(const bf16x8*)(myW + (buf * 16 + l16) * 72 + tl * 32 + q * 8);
#pragma unroll
      for (int mi = 0; mi < 2; mi++) {
        bf16x8 av = *(const bf16x8*)(As + (mi * 16 + l16) * LKA + tau * 32 + q * 8);
        acc[mi] = __builtin_amdgcn_mfma_f32_16x16x32_bf16(av, bv, acc[mi], 0, 0, 0);
      }
    }
    if (g + 1 < total) storeW(g + 1, rr);
    if (g + 3 < total) loadW(g + 3, rr);
  };
  for (int g = 0; g < total; g += 2) {
    step(g, rg1);
    if (g + 1 < total) step(g + 1, rg0);
  }

  if (OUT == 2) {
    __syncthreads();
    float* mlvS = (float*)SM;
#pragma unroll
    for (int mi = 0; mi < 2; mi++)
#pragma unroll
      for (int r = 0; r < 4; r++)
        mlvS[(mi * 16 + q * 4 + r) * 65 + cl] = acc[mi][r];
  } else {  // OUT == 3
#pragma unroll
    for (int mi = 0; mi < 2; mi++)
#pragma unroll
      for (int r = 0; r < 4; r++) {
        float v = acc[mi][r] + bias_s[cl];
        Cb[(mi * 16 + q * 4 + r) * 72 + cl] = f2bf(elu_f(v));
      }
  }
}

// =====================================================================
// prep (one dispatch, 1673 blocks)
__global__ __launch_bounds__(256) void k_prep(MegaArgs a) {
  __shared__ __align__(16) unsigned short T[64][72];
  const int bb = blockIdx.x, tid = threadIdx.x;
  if (bb < 512) {
    for (int rr = 0; rr < 4; rr++) {
      int b = bb * 4 + rr;
      const float* xr = a.x + (size_t)b * 267;
      const float* cr = a.c + (size_t)b * 267;
      unsigned short* axr = a.Ax + (size_t)b * 544;
      for (int k = tid; k < 544; k += 256) {
        float v = (k < 267) ? xr[k] : ((k < 534) ? cr[k - 267] : 0.f);
        axr[k] = f2bf(v);
      }
      unsigned short* ahr = a.Axh + (size_t)b * 544;
      unsigned short* ah2 = a.Axh2 + (size_t)b * 544;
      for (int k = tid; k < 267; k += 256) { unsigned short v = f2bf(xr[k]); ahr[k] = v; ah2[k] = v; }
      for (int k = 523 + tid; k < 544; k += 256) { ahr[k] = 0; ah2[k] = 0; }
      unsigned short* a0r = a.A0 + (size_t)b * 320;
      for (int k = tid; k < 288; k += 256)
        a0r[32 + k] = (k < 267) ? f2bf(cr[k]) : (unsigned short)0;
    }
  } else if (bb < 1152) {
    int r = bb - 512;
    const float* src; unsigned short* dst; int Ks, Kp2;
    if (r < 256)      { src = a.fc1w + (size_t)r * 534; dst = a.fc1t + (size_t)r * 544; Ks = 534; Kp2 = 544; }
    else if (r < 512) { int n = r - 256; src = a.fc2w + (size_t)n * 523; dst = a.fc2t + (size_t)n * 544; Ks = 523; Kp2 = 544; }
    else if (r < 576) { int n = r - 512; src = (n < 32) ? (a.muw + (size_t)n * 523) : (a.lvw + (size_t)(n - 32) * 523);
                        dst = a.mlvt + (size_t)n * 544; Ks = 523; Kp2 = 544; }
    else              { int n = r - 576; src = a.g0w + (size_t)n * 299; dst = a.g0t + (size_t)n * 320; Ks = 299; Kp2 = 320; }
    for (int k = tid; k < Kp2; k += 256) dst[k] = (k < Ks) ? f2bf(src[k]) : (unsigned short)0;
  } else if (bb == 1152) {
    for (int k = tid; k < 4096; k += 256) a.g1t[k] = f2bf(a.g1w[k]);
  } else {
    int t = bb - 1153;
    const float* W; unsigned short* D; int K, N2, Kp2, ldW, e, kt, nt;
    if (t < 160)      { e = t / 20;  int lt = t % 20;  kt = lt / 4; nt = lt % 4; W = a.w0; D = a.w0b; K = 299; N2 = 256; Kp2 = 320; ldW = 256; }
    else if (t < 320) { int u = t - 160; e = u / 20; int lt = u % 20; kt = lt / 4; nt = lt % 4; W = a.w1; D = a.w1b; K = 288; N2 = 256; Kp2 = 288; ldW = 256; }
    else              { int u = t - 320; e = u / 25; int lt = u % 25; kt = lt / 5; nt = lt % 5; W = a.w2; D = a.w2b; K = 288; N2 = 267; Kp2 = 288; ldW = 267; }
    const int k0 = kt * 64, n0 = nt * 64;
    const float* We = W + (size_t)e * K * ldW;
    const int jj = tid & 63, ii0 = tid >> 6;
#pragma unroll
    for (int p = 0; p < 16; p++) {
      int i = ii0 + p * 4;
      int gk = k0 + i, gn = n0 + jj;
      float v = (gk < K && gn < N2) ? We[(size_t)gk * ldW + gn] : 0.f;
      T[jj][i] = f2bf(v);
    }
    __syncthreads();
    int j = tid >> 2, chb = tid & 3;
    int gn = n0 + j;
    if (gn < N2) {
      unsigned short* drow = D + ((size_t)e * N2 + gn) * Kp2 + k0;
#pragma unroll
      for (int s = 0; s < 2; s++) {
        int ch = chb + s * 4;
        if (k0 + ch * 8 < Kp2) {
          i32x4 v = *(i32x4*)(&T[j][ch * 8]);
          *(i32x4*)(drow + ch * 8) = v;
        }
      }
    }
  }
}

// =====================================================================
// mu/lv GEMM + z + full gate stack (verified R4 body), grid 64
__global__ __launch_bounds__(256) void k_mulv_gate(MegaArgs a) {
  __shared__ __align__(16) unsigned char SM[63488];
  const int tid = threadIdx.x, bid = blockIdx.x;
  const int m0 = bid * 32;
  gemm_tile<17, 1, false, 2, false>(SM, tid, a.Axh2, m0, 0, a.mlvt, 64,
                                    nullptr, nullptr, nullptr, 0, 0, nullptr);
  __syncthreads();
  float* mlvS = (float*)SM;
  const int m = tid >> 3, j0 = (tid & 7) * 4;
  const int R = m0 + m;
  unsigned short zb[4];
#pragma unroll
  for (int jj = 0; jj < 4; jj++) {
    int j = j0 + jj;
    float mu = mlvS[m * 65 + j] + a.mub[j];
    float lvv = mlvS[m * 65 + j + 32] + a.lvb[j];
    uint32_t x0 = 0u, x1 = (uint32_t)(R * 32 + j);
    threefry2x32(0u, 42u, x0, x1);
    uint32_t bits = x0 ^ x1;
    float f = __uint_as_float((bits >> 9) | 0x3F800000u) - 1.0f;
    const float lo = -0.99999994039535522461f;
    float u = fmaf(f, 2.0f, lo);
    u = fmaxf(u, lo);
    float eps = 1.41421356237f * erfinv_f(u);
    float z = fmaf(eps, expf(0.5f * lvv), mu);
    a.outMu[(size_t)R * 32 + j] = mu;
    a.outLv[(size_t)R * 32 + j] = lvv;
    zb[jj] = f2bf(z);
    a.A0[(size_t)R * 320 + j] = zb[jj];
    a.A1[(size_t)R * 288 + j] = zb[jj];
    a.A2[(size_t)R * 288 + j] = zb[jj];
  }
  __syncthreads();
  unsigned short* A0p = (unsigned short*)SM;  // [32][328]
  for (int idx = tid; idx < 32 * 36; idx += 256) {
    int row = idx / 36, ch = 4 + idx % 36;
    *(i32x4*)(A0p + row * 328 + ch * 8) =
        *(const i32x4*)(a.A0 + (size_t)(m0 + row) * 320 + ch * 8);
  }
  if (tid < 32) { i32x4 zz; zz[0]=0; zz[1]=0; zz[2]=0; zz[3]=0; *(i32x4*)(A0p + tid * 328 + 320) = zz; }
#pragma unroll
  for (int jj = 0; jj < 4; jj++) A0p[m * 328 + j0 + jj] = zb[jj];
  gemm_tile<10, 1, false, 3, true>(SM, tid, nullptr, 0, 0, a.g0t, 64, a.g0b, nullptr,
                                   (unsigned short*)(SM + 49664), 0, 0, nullptr);
  __syncthreads();
  unsigned short* gaB = (unsigned short*)(SM + 49664);  // [32][72]
  unsigned short* g1B = (unsigned short*)(SM + 54272);  // [64][72]
  for (int idx = tid; idx < 512; idx += 256) {
    int row = idx >> 3, ch = idx & 7;
    *(i32x4*)(g1B + row * 72 + ch * 8) = *(const i32x4*)(a.g1t + (size_t)row * 64 + ch * 8);
  }
  __syncthreads();
  const int lane = tid & 63, wid = tid >> 6, q = lane >> 4, l16 = lane & 15;
  const int cl = wid * 16 + l16;
  f32x4 acc2[2] = {{0,0,0,0},{0,0,0,0}};
#pragma unroll
  for (int tau = 0; tau < 2; tau++) {
    bf16x8 bv = *(const bf16x8*)(g1B + (size_t)cl * 72 + tau * 32 + q * 8);
#pragma unroll
    for (int mi = 0; mi < 2; mi++) {
      bf16x8 av = *(const bf16x8*)(gaB + (mi * 16 + l16) * 72 + tau * 32 + q * 8);
      acc2[mi] = __builtin_amdgcn_mfma_f32_16x16x32_bf16(av, bv, acc2[mi], 0, 0, 0);
    }
  }
  float* gB = (float*)SM;  // [32][65]
  {
    float b1c = a.g1b[cl];
#pragma unroll
    for (int mi = 0; mi < 2; mi++)
#pragma unroll
      for (int r = 0; r < 4; r++)
        gB[(mi * 16 + q * 4 + r) * 65 + cl] = elu_f(acc2[mi][r] + b1c);
  }
  __syncthreads();
  float* lg = (float*)(SM + 8448);  // [32][8]
  {
    int r = tid >> 3, e = tid & 7;
    float acc3 = a.g2b[e];
    for (int k = 0; k < 64; k++) acc3 = fmaf(gB[r * 65 + k], a.g2w[e * 64 + k], acc3);
    lg[r * 8 + e] = acc3;
  }
  __syncthreads();
  if (tid < 32) {
    float mx = lg[tid * 8];
#pragma unroll
    for (int e2 = 1; e2 < 8; e2++) mx = fmaxf(mx, lg[tid * 8 + e2]);
    float s = 0.f, ex[8];
#pragma unroll
    for (int e2 = 0; e2 < 8; e2++) { ex[e2] = expf(lg[tid * 8 + e2] - mx); s += ex[e2]; }
    float inv = 1.f / s;
#pragma unroll
    for (int e2 = 0; e2 < 8; e2++) a.cf[(size_t)(m0 + tid) * 8 + e2] = ex[e2] * inv;
  }
}

// =====================================================================
extern "C" void kernel_launch(void* const* d_in, const int* in_sizes, int n_in,
                              void* d_out, int out_size, void* d_ws, size_t ws_size,
                              hipStream_t stream) {
  (void)in_sizes; (void)n_in; (void)out_size; (void)ws_size;
  float* out = (float*)d_out;
  float* ws = (float*)d_ws;

  MegaArgs a;
  a.x    = (const float*)d_in[0];
  a.c    = (const float*)d_in[1];
  a.fc1w = (const float*)d_in[2];  a.fc1b = (const float*)d_in[3];
  a.fc2w = (const float*)d_in[4];  a.fc2b = (const float*)d_in[5];
  a.muw  = (const float*)d_in[6];  a.mub  = (const float*)d_in[7];
  a.lvw  = (const float*)d_in[8];  a.lvb  = (const float*)d_in[9];
  a.g0w  = (const float*)d_in[10]; a.g0b  = (const float*)d_in[11];
  a.g1w  = (const float*)d_in[12]; a.g1b  = (const float*)d_in[13];
  a.g2w  = (const float*)d_in[14]; a.g2b  = (const float*)d_in[15];
  a.w0   = (const float*)d_in[16]; a.b0   = (const float*)d_in[17];
  a.w1   = (const float*)d_in[18]; a.b1   = (const float*)d_in[19];
  a.w2   = (const float*)d_in[20]; a.b2   = (const float*)d_in[21];

  a.outY  = out;
  a.outMu = out + 2048 * 267;
  a.outLv = a.outMu + 2048 * 32;

  a.Ax   = (unsigned short*)(ws);
  a.Axh  = (unsigned short*)(ws + 557056);
  a.Axh2 = (unsigned short*)(ws + 1114112);
  a.A0   = (unsigned short*)(ws + 1671168);
  a.A1   = (unsigned short*)(ws + 1998848);
  a.A2   = (unsigned short*)(ws + 2293760);
  a.fc1t = (unsigned short*)(ws + 2588672);
  a.fc2t = (unsigned short*)(ws + 2658304);
  a.mlvt = (unsigned short*)(ws + 2727936);
  a.g0t  = (unsigned short*)(ws + 2745344);
  a.g1t  = (unsigned short*)(ws + 2755584);
  a.w0b  = (unsigned short*)(ws + 2757632);
  a.w1b  = (unsigned short*)(ws + 3085312);
  a.w2b  = (unsigned short*)(ws + 3380224);
  a.cf   = ws + 3687808;

  dim3 blk(256);
  k_prep<<<1673, blk, 0, stream>>>(a);
  // fc1 / fc2: KT=17, NE=1
  pipe_gemm<17, 1, true, false, false><<<dim3(64, 4), blk, 0, stream>>>(
      a.Ax, a.fc1t, 256, a.fc1b, nullptr, a.Axh, 544, 267, nullptr);
  pipe_gemm<17, 1, true, false, false><<<dim3(64, 4), blk, 0, stream>>>(
      a.Axh, a.fc2t, 256, a.fc2b, nullptr, a.Axh2, 544, 267, nullptr);
  // mu/lv + z + gate
  k_mulv_gate<<<64, blk, 0, stream>>>(a);
  // MoE decoder
  pipe_gemm<10, 8, true, false, true><<<dim3(64, 4), blk, 0, stream>>>(
      a.A0, a.w0b, 256, a.b0, a.cf, a.A1, 288, 32, nullptr);
  pipe_gemm<9, 8, true, false, true><<<dim3(64, 4), blk, 0, stream>>>(
      a.A1, a.w1b, 256, a.b1, a.cf, a.A2, 288, 32, nullptr);
  pipe_gemm<9, 8, false, true, true><<<dim3(64, 5), blk, 0, stream>>>(
      a.A2, a.w2b, 267, a.b2, a.cf, nullptr, 0, 0, a.outY);
}

// Round 6
// 198.833 us; speedup vs baseline: 2.0873x; 1.0281x over previous
//
#include <hip/hip_runtime.h>
#include <math.h>
#include <stdint.h>

#define DI __device__ __forceinline__

typedef __attribute__((ext_vector_type(8))) short bf16x8;
typedef __attribute__((ext_vector_type(4))) float f32x4;
typedef __attribute__((ext_vector_type(4))) int i32x4;

DI float elu_f(float v) { return v > 0.f ? v : expm1f(v); }

DI unsigned short f2bf(float f) {  // fp32 -> bf16 RNE
  uint32_t u = __float_as_uint(f);
  return (unsigned short)((u + 0x7FFFu + ((u >> 16) & 1u)) >> 16);
}

// ---------------- threefry2x32 (JAX, 20 rounds)
DI void threefry2x32(uint32_t k0, uint32_t k1, uint32_t& x0, uint32_t& x1) {
  uint32_t ks0 = k0, ks1 = k1, ks2 = k0 ^ k1 ^ 0x1BD11BDAu;
  x0 += ks0; x1 += ks1;
#define TFR(r) { x0 += x1; x1 = (x1 << r) | (x1 >> (32 - r)); x1 ^= x0; }
  TFR(13) TFR(15) TFR(26) TFR(6)   x0 += ks1; x1 += ks2 + 1u;
  TFR(17) TFR(29) TFR(16) TFR(24)  x0 += ks2; x1 += ks0 + 2u;
  TFR(13) TFR(15) TFR(26) TFR(6)   x0 += ks0; x1 += ks1 + 3u;
  TFR(17) TFR(29) TFR(16) TFR(24)  x0 += ks1; x1 += ks2 + 4u;
  TFR(13) TFR(15) TFR(26) TFR(6)   x0 += ks2; x1 += ks0 + 5u;
#undef TFR
}

DI float erfinv_f(float x) {  // Giles erfinv (rel err ~1e-6 << bf16 quantum)
  float w = -logf((1.0f - x) * (1.0f + x));
  float p;
  if (w < 5.0f) {
    w -= 2.5f;
    p = 2.81022636e-08f;
    p = fmaf(p, w, 3.43273939e-07f);
    p = fmaf(p, w, -3.5233877e-06f);
    p = fmaf(p, w, -4.39150654e-06f);
    p = fmaf(p, w, 0.00021858087f);
    p = fmaf(p, w, -0.00125372503f);
    p = fmaf(p, w, -0.00417768164f);
    p = fmaf(p, w, 0.246640727f);
    p = fmaf(p, w, 1.50140941f);
  } else {
    w = sqrtf(w) - 3.0f;
    p = -0.000200214257f;
    p = fmaf(p, w, 0.000100950558f);
    p = fmaf(p, w, 0.00134934322f);
    p = fmaf(p, w, -0.00367342844f);
    p = fmaf(p, w, 0.00573950773f);
    p = fmaf(p, w, -0.0076224613f);
    p = fmaf(p, w, 0.00943887047f);
    p = fmaf(p, w, 1.00167406f);
    p = fmaf(p, w, 2.83297682f);
  }
  return p * x;
}

struct MegaArgs {
  const float *x, *c;
  const float *fc1w, *fc1b, *fc2w, *fc2b, *muw, *mub, *lvw, *lvb;
  const float *g0w, *g0b, *g1w, *g1b, *g2w, *g2b;
  const float *w0, *b0, *w1, *b1, *w2, *b2;
  unsigned short *Ax, *Axh, *Axh2, *A0, *A1, *A2;
  unsigned short *fc1t, *fc2t, *mlvt, *g0t, *g1t, *w0b, *w1b, *w2b;
  float *cf, *outY, *outMu, *outLv;
};

// =====================================================================
// pipe_gemm: 32-row x 64-col tile, 4 waves (each 32r x 16c).
// W fragments stream GLOBAL -> register ring (depth D) -> MFMA. No LDS
// round-trip for W, no inner barriers, deep vmcnt pipeline (AITER-style).
template <int KT, int NE, int D, bool ELU, bool OUTF32, bool AREG>
__global__ __launch_bounds__(256, 1)
void pipe_gemm(const unsigned short* __restrict__ A,         // [2048][Kp]
               const unsigned short* __restrict__ Wt, int N, // [NE][N][Kp]
               const float* __restrict__ bias,               // [NE][N]
               const float* __restrict__ cfp,                // [2048][8] | null
               unsigned short* __restrict__ Cb, int ldcb, int cb_off,
               float* __restrict__ Cf) {
  constexpr int Kp = KT * 32, LKA = Kp + 8, CPR = Kp / 8;
  constexpr int TT = NE * KT;
  __shared__ unsigned short As[32 * LKA];
  __shared__ float bias_s[NE * 64];
  __shared__ float cfs[256];
  const int tid = threadIdx.x, lane = tid & 63, wid = tid >> 6;
  const int q = lane >> 4, l16 = lane & 15;
  const int m0 = blockIdx.x * 32, n0 = blockIdx.y * 64;
  const int cl = wid * 16 + l16;
  const int gc = n0 + cl;
  const int wrow = (gc < N) ? gc : (N - 1);  // clamp: OOB lanes load junk, never stored

  const unsigned short* wlane = Wt + (size_t)wrow * Kp + q * 8;

  bf16x8 ring[D];
#pragma unroll
  for (int g = 0; g < D; g++) {
    if (g < TT) {
      int e = g / KT, c = g % KT;
      ring[g] = *(const bf16x8*)(wlane + (size_t)e * N * Kp + c * 32);
    }
  }
  for (int idx = tid; idx < 32 * CPR; idx += 256) {
    int row = idx / CPR, ch = idx % CPR;
    *(i32x4*)(As + row * LKA + ch * 8) =
        *(const i32x4*)(A + (size_t)(m0 + row) * Kp + ch * 8);
  }
  for (int idx = tid; idx < NE * 64; idx += 256) {
    int e = idx >> 6, col = idx & 63;
    bias_s[idx] = (n0 + col < N) ? bias[(size_t)e * N + n0 + col] : 0.f;
  }
  if (NE > 1) cfs[tid] = cfp[(size_t)(m0 + (tid >> 3)) * 8 + (tid & 7)];
  __syncthreads();

  bf16x8 areg[AREG ? 2 * KT : 1];
  if (AREG) {
#pragma unroll
    for (int c = 0; c < KT; c++)
#pragma unroll
      for (int mi = 0; mi < 2; mi++)
        areg[c * 2 + mi] = *(const bf16x8*)(As + (mi * 16 + l16) * LKA + c * 32 + q * 8);
  }

  f32x4 acc[2] = {{0, 0, 0, 0}, {0, 0, 0, 0}};
  f32x4 accF[2] = {{0, 0, 0, 0}, {0, 0, 0, 0}};
#pragma unroll
  for (int g = 0; g < TT; g++) {
    const int e = g / KT, c = g % KT;
    bf16x8 bv = ring[g % D];
#pragma unroll
    for (int mi = 0; mi < 2; mi++) {
      bf16x8 av = AREG ? areg[c * 2 + mi]
                       : *(const bf16x8*)(As + (mi * 16 + l16) * LKA + c * 32 + q * 8);
      acc[mi] = __builtin_amdgcn_mfma_f32_16x16x32_bf16(av, bv, acc[mi], 0, 0, 0);
    }
    if (g + D < TT) {
      int e2 = (g + D) / KT, c2 = (g + D) % KT;
      ring[g % D] = *(const bf16x8*)(wlane + (size_t)e2 * N * Kp + c2 * 32);
    }
    if (NE > 1 && c == KT - 1) {  // expert boundary: exact fp32 fold
      float bv2 = bias_s[e * 64 + cl];
#pragma unroll
      for (int mi = 0; mi < 2; mi++)
#pragma unroll
        for (int r = 0; r < 4; r++) {
          float ce = cfs[(mi * 16 + q * 4 + r) * 8 + e];
          accF[mi][r] += ce * (acc[mi][r] + bv2);
          acc[mi][r] = 0.f;
        }
    }
  }

  if (gc < N) {
#pragma unroll
    for (int mi = 0; mi < 2; mi++)
#pragma unroll
      for (int r = 0; r < 4; r++) {
        int row = m0 + mi * 16 + q * 4 + r;
        float v = (NE > 1) ? accF[mi][r] : (acc[mi][r] + bias_s[cl]);
        if (ELU) v = elu_f(v);
        if (OUTF32) Cf[(size_t)row * 267 + gc] = v;
        else Cb[(size_t)row * ldcb + cb_off + gc] = f2bf(v);
      }
  }
}

// =====================================================================
// prep (one dispatch, 1673 blocks) — unchanged from R5
__global__ __launch_bounds__(256) void k_prep(MegaArgs a) {
  __shared__ __align__(16) unsigned short T[64][72];
  const int bb = blockIdx.x, tid = threadIdx.x;
  if (bb < 512) {
    for (int rr = 0; rr < 4; rr++) {
      int b = bb * 4 + rr;
      const float* xr = a.x + (size_t)b * 267;
      const float* cr = a.c + (size_t)b * 267;
      unsigned short* axr = a.Ax + (size_t)b * 544;
      for (int k = tid; k < 544; k += 256) {
        float v = (k < 267) ? xr[k] : ((k < 534) ? cr[k - 267] : 0.f);
        axr[k] = f2bf(v);
      }
      unsigned short* ahr = a.Axh + (size_t)b * 544;
      unsigned short* ah2 = a.Axh2 + (size_t)b * 544;
      for (int k = tid; k < 267; k += 256) { unsigned short v = f2bf(xr[k]); ahr[k] = v; ah2[k] = v; }
      for (int k = 523 + tid; k < 544; k += 256) { ahr[k] = 0; ah2[k] = 0; }
      unsigned short* a0r = a.A0 + (size_t)b * 320;
      for (int k = tid; k < 288; k += 256)
        a0r[32 + k] = (k < 267) ? f2bf(cr[k]) : (unsigned short)0;
    }
  } else if (bb < 1152) {
    int r = bb - 512;
    const float* src; unsigned short* dst; int Ks, Kp2;
    if (r < 256)      { src = a.fc1w + (size_t)r * 534; dst = a.fc1t + (size_t)r * 544; Ks = 534; Kp2 = 544; }
    else if (r < 512) { int n = r - 256; src = a.fc2w + (size_t)n * 523; dst = a.fc2t + (size_t)n * 544; Ks = 523; Kp2 = 544; }
    else if (r < 576) { int n = r - 512; src = (n < 32) ? (a.muw + (size_t)n * 523) : (a.lvw + (size_t)(n - 32) * 523);
                        dst = a.mlvt + (size_t)n * 544; Ks = 523; Kp2 = 544; }
    else              { int n = r - 576; src = a.g0w + (size_t)n * 299; dst = a.g0t + (size_t)n * 320; Ks = 299; Kp2 = 320; }
    for (int k = tid; k < Kp2; k += 256) dst[k] = (k < Ks) ? f2bf(src[k]) : (unsigned short)0;
  } else if (bb == 1152) {
    for (int k = tid; k < 4096; k += 256) a.g1t[k] = f2bf(a.g1w[k]);
  } else {
    int t = bb - 1153;
    const float* W; unsigned short* D; int K, N2, Kp2, ldW, e, kt, nt;
    if (t < 160)      { e = t / 20;  int lt = t % 20;  kt = lt / 4; nt = lt % 4; W = a.w0; D = a.w0b; K = 299; N2 = 256; Kp2 = 320; ldW = 256; }
    else if (t < 320) { int u = t - 160; e = u / 20; int lt = u % 20; kt = lt / 4; nt = lt % 4; W = a.w1; D = a.w1b; K = 288; N2 = 256; Kp2 = 288; ldW = 256; }
    else              { int u = t - 320; e = u / 25; int lt = u % 25; kt = lt / 5; nt = lt % 5; W = a.w2; D = a.w2b; K = 288; N2 = 267; Kp2 = 288; ldW = 267; }
    const int k0 = kt * 64, n0 = nt * 64;
    const float* We = W + (size_t)e * K * ldW;
    const int jj = tid & 63, ii0 = tid >> 6;
#pragma unroll
    for (int p = 0; p < 16; p++) {
      int i = ii0 + p * 4;
      int gk = k0 + i, gn = n0 + jj;
      float v = (gk < K && gn < N2) ? We[(size_t)gk * ldW + gn] : 0.f;
      T[jj][i] = f2bf(v);
    }
    __syncthreads();
    int j = tid >> 2, chb = tid & 3;
    int gn = n0 + j;
    if (gn < N2) {
      unsigned short* drow = D + ((size_t)e * N2 + gn) * Kp2 + k0;
#pragma unroll
      for (int s = 0; s < 2; s++) {
        int ch = chb + s * 4;
        if (k0 + ch * 8 < Kp2) {
          i32x4 v = *(i32x4*)(&T[j][ch * 8]);
          *(i32x4*)(drow + ch * 8) = v;
        }
      }
    }
  }
}

// =====================================================================
// mu/lv GEMM + z + full gate stack — ALL pipe/ring based, 64 blocks x 32 rows
__global__ __launch_bounds__(256, 1) void k_mulv_gate(MegaArgs a) {
  __shared__ __align__(16) unsigned char SM[64640];
  unsigned short* As  = (unsigned short*)SM;            // [32][552]  (phase A)
  unsigned short* A0p = (unsigned short*)(SM + 35328);  // [32][328]
  float* mlvS = (float*)(SM + 56320);                   // [32][65]
  // overlays on As region (dead after phase A)
  unsigned short* gaB = (unsigned short*)SM;            // [32][72]
  unsigned short* g1B = (unsigned short*)(SM + 4608);   // [64][72]
  float* g2wT = (float*)(SM + 13824);                   // [64][8]
  float* lg   = (float*)(SM + 15872);                   // [32][8]
  float* gB   = (float*)(SM + 16896);                   // [32][65]

  const int tid = threadIdx.x, lane = tid & 63, wid = tid >> 6;
  const int q = lane >> 4, l16 = lane & 15;
  const int m0 = blockIdx.x * 32;
  const int cl = wid * 16 + l16;  // 0..63

  // ---- phase A: mu/lv pipe GEMM (A=Axh2[32x544], W=mlvt[64][544], TT=17) ----
  const unsigned short* wlA = a.mlvt + (size_t)cl * 544 + q * 8;
  bf16x8 ring[8];
#pragma unroll
  for (int g = 0; g < 8; g++) ring[g] = *(const bf16x8*)(wlA + g * 32);
  for (int idx = tid; idx < 32 * 68; idx += 256) {
    int row = idx / 68, ch = idx % 68;
    *(i32x4*)(As + row * 552 + ch * 8) =
        *(const i32x4*)(a.Axh2 + (size_t)(m0 + row) * 544 + ch * 8);
  }
  for (int idx = tid; idx < 32 * 36; idx += 256) {  // A0p c-part (cols 32..319)
    int row = idx / 36, ch = 4 + idx % 36;
    *(i32x4*)(A0p + row * 328 + ch * 8) =
        *(const i32x4*)(a.A0 + (size_t)(m0 + row) * 320 + ch * 8);
  }
  __syncthreads();
  f32x4 acc[2] = {{0, 0, 0, 0}, {0, 0, 0, 0}};
#pragma unroll
  for (int g = 0; g < 17; g++) {
    bf16x8 bv = ring[g % 8];
#pragma unroll
    for (int mi = 0; mi < 2; mi++) {
      bf16x8 av = *(const bf16x8*)(As + (mi * 16 + l16) * 552 + g * 32 + q * 8);
      acc[mi] = __builtin_amdgcn_mfma_f32_16x16x32_bf16(av, bv, acc[mi], 0, 0, 0);
    }
    if (g + 8 < 17) ring[g % 8] = *(const bf16x8*)(wlA + (g + 8) * 32);
  }
#pragma unroll
  for (int mi = 0; mi < 2; mi++)
#pragma unroll
    for (int r = 0; r < 4; r++)
      mlvS[(mi * 16 + q * 4 + r) * 65 + cl] = acc[mi][r];
  __syncthreads();

  // ---- phase B: z (exact JAX threefry-normal) + stage g1/g2 weights ----
  {
    const int m = tid >> 3, j0 = (tid & 7) * 4, R = m0 + m;
#pragma unroll
    for (int jj = 0; jj < 4; jj++) {
      int j = j0 + jj;
      float mu = mlvS[m * 65 + j] + a.mub[j];
      float lvv = mlvS[m * 65 + j + 32] + a.lvb[j];
      uint32_t x0 = 0u, x1 = (uint32_t)(R * 32 + j);
      threefry2x32(0u, 42u, x0, x1);
      uint32_t bits = x0 ^ x1;
      float f = __uint_as_float((bits >> 9) | 0x3F800000u) - 1.0f;
      const float lo = -0.99999994039535522461f;
      float u = fmaf(f, 2.0f, lo);
      u = fmaxf(u, lo);
      float eps = 1.41421356237f * erfinv_f(u);
      float z = fmaf(eps, expf(0.5f * lvv), mu);
      a.outMu[(size_t)R * 32 + j] = mu;
      a.outLv[(size_t)R * 32 + j] = lvv;
      unsigned short zb = f2bf(z);
      A0p[m * 328 + j] = zb;
      a.A0[(size_t)R * 320 + j] = zb;
      a.A1[(size_t)R * 288 + j] = zb;
      a.A2[(size_t)R * 288 + j] = zb;
    }
  }
  for (int idx = tid; idx < 512; idx += 256) {  // g1B [64][72]
    int row = idx >> 3, ch = idx & 7;
    *(i32x4*)(g1B + row * 72 + ch * 8) = *(const i32x4*)(a.g1t + (size_t)row * 64 + ch * 8);
  }
  for (int idx = tid; idx < 512; idx += 256)    // g2w transposed [64][8]
    g2wT[(idx & 63) * 8 + (idx >> 6)] = a.g2w[idx];
  __syncthreads();

  // ---- phase C: g0 pipe GEMM (A=A0p[32x320], W=g0t[64][320], TT=10) ----
  const unsigned short* wlC = a.g0t + (size_t)cl * 320 + q * 8;
  bf16x8 ring2[8];
#pragma unroll
  for (int g = 0; g < 8; g++) ring2[g] = *(const bf16x8*)(wlC + g * 32);
  f32x4 accC[2] = {{0, 0, 0, 0}, {0, 0, 0, 0}};
#pragma unroll
  for (int g = 0; g < 10; g++) {
    bf16x8 bv = ring2[g % 8];
#pragma unroll
    for (int mi = 0; mi < 2; mi++) {
      bf16x8 av = *(const bf16x8*)(A0p + (mi * 16 + l16) * 328 + g * 32 + q * 8);
      accC[mi] = __builtin_amdgcn_mfma_f32_16x16x32_bf16(av, bv, accC[mi], 0, 0, 0);
    }
    if (g + 8 < 10) ring2[g % 8] = *(const bf16x8*)(wlC + (g + 8) * 32);
  }
  {
    float bc = a.g0b[cl];
#pragma unroll
    for (int mi = 0; mi < 2; mi++)
#pragma unroll
      for (int r = 0; r < 4; r++)
        gaB[(mi * 16 + q * 4 + r) * 72 + cl] = f2bf(elu_f(accC[mi][r] + bc));
  }
  __syncthreads();

  // ---- phase D: g1 (A=gaB[32][72] bf16, W=g1B[64][72]) ----
  f32x4 acc2[2] = {{0, 0, 0, 0}, {0, 0, 0, 0}};
#pragma unroll
  for (int tau = 0; tau < 2; tau++) {
    bf16x8 bv = *(const bf16x8*)(g1B + (size_t)cl * 72 + tau * 32 + q * 8);
#pragma unroll
    for (int mi = 0; mi < 2; mi++) {
      bf16x8 av = *(const bf16x8*)(gaB + (mi * 16 + l16) * 72 + tau * 32 + q * 8);
      acc2[mi] = __builtin_amdgcn_mfma_f32_16x16x32_bf16(av, bv, acc2[mi], 0, 0, 0);
    }
  }
  {
    float bc = a.g1b[cl];
#pragma unroll
    for (int mi = 0; mi < 2; mi++)
#pragma unroll
      for (int r = 0; r < 4; r++)
        gB[(mi * 16 + q * 4 + r) * 65 + cl] = elu_f(acc2[mi][r] + bc);
  }
  __syncthreads();

  // ---- phase E: g2 logits + softmax -> cf ----
  {
    int r = tid >> 3, e = tid & 7;
    float d = a.g2b[e];
#pragma unroll 8
    for (int k = 0; k < 64; k++) d = fmaf(gB[r * 65 + k], g2wT[k * 8 + e], d);
    lg[r * 8 + e] = d;
  }
  __syncthreads();
  if (tid < 32) {
    float mx = lg[tid * 8];
#pragma unroll
    for (int e2 = 1; e2 < 8; e2++) mx = fmaxf(mx, lg[tid * 8 + e2]);
    float s = 0.f, ex[8];
#pragma unroll
    for (int e2 = 0; e2 < 8; e2++) { ex[e2] = expf(lg[tid * 8 + e2] - mx); s += ex[e2]; }
    float inv = 1.f / s;
#pragma unroll
    for (int e2 = 0; e2 < 8; e2++) a.cf[(size_t)(m0 + tid) * 8 + e2] = ex[e2] * inv;
  }
}

// =====================================================================
extern "C" void kernel_launch(void* const* d_in, const int* in_sizes, int n_in,
                              void* d_out, int out_size, void* d_ws, size_t ws_size,
                              hipStream_t stream) {
  (void)in_sizes; (void)n_in; (void)out_size; (void)ws_size;
  float* out = (float*)d_out;
  float* ws = (float*)d_ws;

  MegaArgs a;
  a.x    = (const float*)d_in[0];
  a.c    = (const float*)d_in[1];
  a.fc1w = (const float*)d_in[2];  a.fc1b = (const float*)d_in[3];
  a.fc2w = (const float*)d_in[4];  a.fc2b = (const float*)d_in[5];
  a.muw  = (const float*)d_in[6];  a.mub  = (const float*)d_in[7];
  a.lvw  = (const float*)d_in[8];  a.lvb  = (const float*)d_in[9];
  a.g0w  = (const float*)d_in[10]; a.g0b  = (const float*)d_in[11];
  a.g1w  = (const float*)d_in[12]; a.g1b  = (const float*)d_in[13];
  a.g2w  = (const float*)d_in[14]; a.g2b  = (const float*)d_in[15];
  a.w0   = (const float*)d_in[16]; a.b0   = (const float*)d_in[17];
  a.w1   = (const float*)d_in[18]; a.b1   = (const float*)d_in[19];
  a.w2   = (const float*)d_in[20]; a.b2   = (const float*)d_in[21];

  a.outY  = out;
  a.outMu = out + 2048 * 267;
  a.outLv = a.outMu + 2048 * 32;

  a.Ax   = (unsigned short*)(ws);
  a.Axh  = (unsigned short*)(ws + 557056);
  a.Axh2 = (unsigned short*)(ws + 1114112);
  a.A0   = (unsigned short*)(ws + 1671168);
  a.A1   = (unsigned short*)(ws + 1998848);
  a.A2   = (unsigned short*)(ws + 2293760);
  a.fc1t = (unsigned short*)(ws + 2588672);
  a.fc2t = (unsigned short*)(ws + 2658304);
  a.mlvt = (unsigned short*)(ws + 2727936);
  a.g0t  = (unsigned short*)(ws + 2745344);
  a.g1t  = (unsigned short*)(ws + 2755584);
  a.w0b  = (unsigned short*)(ws + 2757632);
  a.w1b  = (unsigned short*)(ws + 3085312);
  a.w2b  = (unsigned short*)(ws + 3380224);
  a.cf   = ws + 3687808;

  dim3 blk(256);
  k_prep<<<1673, blk, 0, stream>>>(a);
  pipe_gemm<17, 1, 12, true, false, false><<<dim3(64, 4), blk, 0, stream>>>(
      a.Ax, a.fc1t, 256, a.fc1b, nullptr, a.Axh, 544, 267, nullptr);
  pipe_gemm<17, 1, 12, true, false, false><<<dim3(64, 4), blk, 0, stream>>>(
      a.Axh, a.fc2t, 256, a.fc2b, nullptr, a.Axh2, 544, 267, nullptr);
  k_mulv_gate<<<64, blk, 0, stream>>>(a);
  pipe_gemm<10, 8, 16, true, false, true><<<dim3(64, 4), blk, 0, stream>>>(
      a.A0, a.w0b, 256, a.b0, a.cf, a.A1, 288, 32, nullptr);
  pipe_gemm<9, 8, 16, true, false, true><<<dim3(64, 4), blk, 0, stream>>>(
      a.A1, a.w1b, 256, a.b1, a.cf, a.A2, 288, 32, nullptr);
  pipe_gemm<9, 8, 16, false, true, true><<<dim3(64, 5), blk, 0, stream>>>(
      a.A2, a.w2b, 267, a.b2, a.cf, nullptr, 0, 0, a.outY);
}

// Round 7
// 182.795 us; speedup vs baseline: 2.2705x; 1.0877x over previous
//
#include <hip/hip_runtime.h>
#include <math.h>
#include <stdint.h>

#define DI __device__ __forceinline__

typedef __attribute__((ext_vector_type(8))) short bf16x8;
typedef __attribute__((ext_vector_type(4))) float f32x4;
typedef __attribute__((ext_vector_type(4))) int i32x4;

DI float elu_f(float v) { return v > 0.f ? v : expm1f(v); }

DI unsigned short f2bf(float f) {  // fp32 -> bf16 RNE
  uint32_t u = __float_as_uint(f);
  return (unsigned short)((u + 0x7FFFu + ((u >> 16) & 1u)) >> 16);
}

// ---------------- threefry2x32 (JAX, 20 rounds)
DI void threefry2x32(uint32_t k0, uint32_t k1, uint32_t& x0, uint32_t& x1) {
  uint32_t ks0 = k0, ks1 = k1, ks2 = k0 ^ k1 ^ 0x1BD11BDAu;
  x0 += ks0; x1 += ks1;
#define TFR(r) { x0 += x1; x1 = (x1 << r) | (x1 >> (32 - r)); x1 ^= x0; }
  TFR(13) TFR(15) TFR(26) TFR(6)   x0 += ks1; x1 += ks2 + 1u;
  TFR(17) TFR(29) TFR(16) TFR(24)  x0 += ks2; x1 += ks0 + 2u;
  TFR(13) TFR(15) TFR(26) TFR(6)   x0 += ks0; x1 += ks1 + 3u;
  TFR(17) TFR(29) TFR(16) TFR(24)  x0 += ks1; x1 += ks2 + 4u;
  TFR(13) TFR(15) TFR(26) TFR(6)   x0 += ks2; x1 += ks0 + 5u;
#undef TFR
}

DI float erfinv_f(float x) {  // Giles erfinv (rel err ~1e-6 << bf16 quantum)
  float w = -logf((1.0f - x) * (1.0f + x));
  float p;
  if (w < 5.0f) {
    w -= 2.5f;
    p = 2.81022636e-08f;
    p = fmaf(p, w, 3.43273939e-07f);
    p = fmaf(p, w, -3.5233877e-06f);
    p = fmaf(p, w, -4.39150654e-06f);
    p = fmaf(p, w, 0.00021858087f);
    p = fmaf(p, w, -0.00125372503f);
    p = fmaf(p, w, -0.00417768164f);
    p = fmaf(p, w, 0.246640727f);
    p = fmaf(p, w, 1.50140941f);
  } else {
    w = sqrtf(w) - 3.0f;
    p = -0.000200214257f;
    p = fmaf(p, w, 0.000100950558f);
    p = fmaf(p, w, 0.00134934322f);
    p = fmaf(p, w, -0.00367342844f);
    p = fmaf(p, w, 0.00573950773f);
    p = fmaf(p, w, -0.0076224613f);
    p = fmaf(p, w, 0.00943887047f);
    p = fmaf(p, w, 1.00167406f);
    p = fmaf(p, w, 2.83297682f);
  }
  return p * x;
}

struct MegaArgs {
  const float *x, *c;
  const float *fc1w, *fc1b, *fc2w, *fc2b, *muw, *mub, *lvw, *lvb;
  const float *g0w, *g0b, *g1w, *g1b, *g2w, *g2b;
  const float *w0, *b0, *w1, *b1, *w2, *b2;
  unsigned short *Ax, *Axh, *Axh2, *A0, *A1, *A2;
  unsigned short *fc1t, *fc2t, *mlvt, *g0t, *g1t, *w0b, *w1b, *w2b;
  float *cf, *outY, *outMu, *outLv;
};

// =====================================================================
// pipe16: 32-row x 16-col tile, 128 threads = 2 waves (wave w = rows w*16..+16).
// ALL GEMM operands register-resident: A-frags direct global->VGPR (one
// instruction = 16 fully-used 64B lines), W streamed via register ring.
// LDS only for bias/coeff. 2 waves/SIMD occupancy via __launch_bounds__(128,2).
template <int KT, int NE, int D, bool ELU, bool OUTF32>
__global__ __launch_bounds__(128, 2)
void pipe16(const unsigned short* __restrict__ A,          // [2048][Kp]
            const unsigned short* __restrict__ Wt, int N,  // [NE][N][Kp]
            const float* __restrict__ bias,                // [NE][N]
            const float* __restrict__ cfp,                 // [2048][8] | null
            unsigned short* __restrict__ Cb, int ldcb, int cb_off,
            float* __restrict__ Cf) {
  constexpr int Kp = KT * 32, TT = NE * KT;
  __shared__ float bias_s[NE * 16];
  __shared__ float cfs[(NE > 1) ? 256 : 1];
  const int tid = threadIdx.x, lane = tid & 63, wid = tid >> 6;  // wid 0,1
  const int q = lane >> 4, l16 = lane & 15;
  const int m0 = blockIdx.x * 32, n0 = blockIdx.y * 16;
  const int gc = n0 + l16;
  const int wrow = (gc < N) ? gc : (N - 1);  // clamp: OOB lanes load junk, never stored
  const unsigned short* wlane = Wt + (size_t)wrow * Kp + q * 8;
  const unsigned short* alane = A + (size_t)(m0 + wid * 16 + l16) * Kp + q * 8;

  bf16x8 ring[D];
#pragma unroll
  for (int g = 0; g < D; g++) {
    if (g < TT) {
      int e = g / KT, c = g % KT;
      ring[g] = *(const bf16x8*)(wlane + (size_t)e * N * Kp + c * 32);
    }
  }
  bf16x8 areg[KT];
#pragma unroll
  for (int c = 0; c < KT; c++) areg[c] = *(const bf16x8*)(alane + c * 32);

  if (NE == 1) {
    if (tid < 16) bias_s[tid] = (n0 + tid < N) ? bias[n0 + tid] : 0.f;
  } else {
    if (tid < NE * 16) {
      int e = tid >> 4, col = tid & 15;
      bias_s[tid] = (n0 + col < N) ? bias[(size_t)e * N + n0 + col] : 0.f;
    }
    for (int idx = tid; idx < 256; idx += 128)
      cfs[idx] = cfp[(size_t)(m0 + (idx >> 3)) * 8 + (idx & 7)];
  }
  __syncthreads();

  f32x4 acc = {0.f, 0.f, 0.f, 0.f}, accF = {0.f, 0.f, 0.f, 0.f};
#pragma unroll
  for (int g = 0; g < TT; g++) {
    const int e = g / KT, c = g % KT;
    acc = __builtin_amdgcn_mfma_f32_16x16x32_bf16(areg[c], ring[g % D], acc, 0, 0, 0);
    if (g + D < TT) {
      int e2 = (g + D) / KT, c2 = (g + D) % KT;
      ring[g % D] = *(const bf16x8*)(wlane + (size_t)e2 * N * Kp + c2 * 32);
    }
    if (NE > 1 && c == KT - 1) {  // expert boundary: exact fp32 fold
      float bv2 = bias_s[e * 16 + l16];
#pragma unroll
      for (int r = 0; r < 4; r++) {
        float ce = cfs[(wid * 16 + q * 4 + r) * 8 + e];
        accF[r] += ce * (acc[r] + bv2);
        acc[r] = 0.f;
      }
    }
  }

  if (gc < N) {
#pragma unroll
    for (int r = 0; r < 4; r++) {
      int row = m0 + wid * 16 + q * 4 + r;
      float v = (NE > 1) ? accF[r] : (acc[r] + bias_s[l16]);
      if (ELU) v = elu_f(v);
      if (OUTF32) Cf[(size_t)row * 267 + gc] = v;
      else Cb[(size_t)row * ldcb + cb_off + gc] = f2bf(v);
    }
  }
}

// =====================================================================
// prep (one dispatch, 1673 blocks) — unchanged (verified R5/R6)
__global__ __launch_bounds__(256) void k_prep(MegaArgs a) {
  __shared__ __align__(16) unsigned short T[64][72];
  const int bb = blockIdx.x, tid = threadIdx.x;
  if (bb < 512) {
    for (int rr = 0; rr < 4; rr++) {
      int b = bb * 4 + rr;
      const float* xr = a.x + (size_t)b * 267;
      const float* cr = a.c + (size_t)b * 267;
      unsigned short* axr = a.Ax + (size_t)b * 544;
      for (int k = tid; k < 544; k += 256) {
        float v = (k < 267) ? xr[k] : ((k < 534) ? cr[k - 267] : 0.f);
        axr[k] = f2bf(v);
      }
      unsigned short* ahr = a.Axh + (size_t)b * 544;
      unsigned short* ah2 = a.Axh2 + (size_t)b * 544;
      for (int k = tid; k < 267; k += 256) { unsigned short v = f2bf(xr[k]); ahr[k] = v; ah2[k] = v; }
      for (int k = 523 + tid; k < 544; k += 256) { ahr[k] = 0; ah2[k] = 0; }
      unsigned short* a0r = a.A0 + (size_t)b * 320;
      for (int k = tid; k < 288; k += 256)
        a0r[32 + k] = (k < 267) ? f2bf(cr[k]) : (unsigned short)0;
    }
  } else if (bb < 1152) {
    int r = bb - 512;
    const float* src; unsigned short* dst; int Ks, Kp2;
    if (r < 256)      { src = a.fc1w + (size_t)r * 534; dst = a.fc1t + (size_t)r * 544; Ks = 534; Kp2 = 544; }
    else if (r < 512) { int n = r - 256; src = a.fc2w + (size_t)n * 523; dst = a.fc2t + (size_t)n * 544; Ks = 523; Kp2 = 544; }
    else if (r < 576) { int n = r - 512; src = (n < 32) ? (a.muw + (size_t)n * 523) : (a.lvw + (size_t)(n - 32) * 523);
                        dst = a.mlvt + (size_t)n * 544; Ks = 523; Kp2 = 544; }
    else              { int n = r - 576; src = a.g0w + (size_t)n * 299; dst = a.g0t + (size_t)n * 320; Ks = 299; Kp2 = 320; }
    for (int k = tid; k < Kp2; k += 256) dst[k] = (k < Ks) ? f2bf(src[k]) : (unsigned short)0;
  } else if (bb == 1152) {
    for (int k = tid; k < 4096; k += 256) a.g1t[k] = f2bf(a.g1w[k]);
  } else {
    int t = bb - 1153;
    const float* W; unsigned short* D; int K, N2, Kp2, ldW, e, kt, nt;
    if (t < 160)      { e = t / 20;  int lt = t % 20;  kt = lt / 4; nt = lt % 4; W = a.w0; D = a.w0b; K = 299; N2 = 256; Kp2 = 320; ldW = 256; }
    else if (t < 320) { int u = t - 160; e = u / 20; int lt = u % 20; kt = lt / 4; nt = lt % 4; W = a.w1; D = a.w1b; K = 288; N2 = 256; Kp2 = 288; ldW = 256; }
    else              { int u = t - 320; e = u / 25; int lt = u % 25; kt = lt / 5; nt = lt % 5; W = a.w2; D = a.w2b; K = 288; N2 = 267; Kp2 = 288; ldW = 267; }
    const int k0 = kt * 64, n0 = nt * 64;
    const float* We = W + (size_t)e * K * ldW;
    const int jj = tid & 63, ii0 = tid >> 6;
#pragma unroll
    for (int p = 0; p < 16; p++) {
      int i = ii0 + p * 4;
      int gk = k0 + i, gn = n0 + jj;
      float v = (gk < K && gn < N2) ? We[(size_t)gk * ldW + gn] : 0.f;
      T[jj][i] = f2bf(v);
    }
    __syncthreads();
    int j = tid >> 2, chb = tid & 3;
    int gn = n0 + j;
    if (gn < N2) {
      unsigned short* drow = D + ((size_t)e * N2 + gn) * Kp2 + k0;
#pragma unroll
      for (int s = 0; s < 2; s++) {
        int ch = chb + s * 4;
        if (k0 + ch * 8 < Kp2) {
          i32x4 v = *(i32x4*)(&T[j][ch * 8]);
          *(i32x4*)(drow + ch * 8) = v;
        }
      }
    }
  }
}

// =====================================================================
// mu/lv GEMM + z + full gate stack — 128 blocks x 16 rows, register GEMMs
__global__ __launch_bounds__(256, 2) void k_mulv_gate(MegaArgs a) {
  __shared__ float mlvS[16 * 65];
  __shared__ __align__(16) unsigned short A0p[16 * 328];
  __shared__ __align__(16) unsigned short gaB[16 * 72];
  __shared__ __align__(16) unsigned short g1B[64 * 72];
  __shared__ float g2wT[64 * 8];
  __shared__ float gB[16 * 65];
  __shared__ float lg[16 * 8];
  const int tid = threadIdx.x, lane = tid & 63, wid = tid >> 6;
  const int q = lane >> 4, l16 = lane & 15;
  const int m0 = blockIdx.x * 16;
  const int cl = wid * 16 + l16;  // 0..63

  // ---- phase A: mu/lv (rows m0..+16 of Axh2, all 64 out-cols = mu|lv) ----
  const unsigned short* alane = a.Axh2 + (size_t)(m0 + l16) * 544 + q * 8;
  const unsigned short* wlA = a.mlvt + (size_t)cl * 544 + q * 8;
  bf16x8 ring[8];
#pragma unroll
  for (int g = 0; g < 8; g++) ring[g] = *(const bf16x8*)(wlA + g * 32);
  bf16x8 areg[17];
#pragma unroll
  for (int c = 0; c < 17; c++) areg[c] = *(const bf16x8*)(alane + c * 32);
  f32x4 acc = {0.f, 0.f, 0.f, 0.f};
#pragma unroll
  for (int g = 0; g < 17; g++) {
    acc = __builtin_amdgcn_mfma_f32_16x16x32_bf16(areg[g], ring[g % 8], acc, 0, 0, 0);
    if (g + 8 < 17) ring[g % 8] = *(const bf16x8*)(wlA + (g + 8) * 32);
  }
#pragma unroll
  for (int r = 0; r < 4; r++) mlvS[(q * 4 + r) * 65 + cl] = acc[r];
  // concurrently stage A0p c-part (cols 32..319), zero-pad, g1B, g2wT
  for (int idx = tid; idx < 576; idx += 256) {
    int row = idx / 36, ch = 4 + idx % 36;
    *(i32x4*)(A0p + row * 328 + ch * 8) =
        *(const i32x4*)(a.A0 + (size_t)(m0 + row) * 320 + ch * 8);
  }
  if (tid < 16) { i32x4 z4 = {0, 0, 0, 0}; *(i32x4*)(A0p + tid * 328 + 320) = z4; }
  for (int idx = tid; idx < 512; idx += 256) {
    int row = idx >> 3, ch = idx & 7;
    *(i32x4*)(g1B + row * 72 + ch * 8) = *(const i32x4*)(a.g1t + (size_t)row * 64 + ch * 8);
  }
  for (int idx = tid; idx < 512; idx += 256)
    g2wT[(idx & 63) * 8 + (idx >> 6)] = a.g2w[idx];
  __syncthreads();

  // ---- phase B: z = mu + eps*exp(0.5*lv) (exact JAX threefry-normal) ----
  {
    const int m = tid >> 4, j0 = (tid & 15) * 2, R = m0 + m;
#pragma unroll
    for (int jj = 0; jj < 2; jj++) {
      int j = j0 + jj;
      float mu = mlvS[m * 65 + j] + a.mub[j];
      float lvv = mlvS[m * 65 + j + 32] + a.lvb[j];
      uint32_t x0 = 0u, x1 = (uint32_t)(R * 32 + j);
      threefry2x32(0u, 42u, x0, x1);
      uint32_t bits = x0 ^ x1;
      float f = __uint_as_float((bits >> 9) | 0x3F800000u) - 1.0f;
      const float lo = -0.99999994039535522461f;
      float u = fmaf(f, 2.0f, lo);
      u = fmaxf(u, lo);
      float eps = 1.41421356237f * erfinv_f(u);
      float z = fmaf(eps, expf(0.5f * lvv), mu);
      a.outMu[(size_t)R * 32 + j] = mu;
      a.outLv[(size_t)R * 32 + j] = lvv;
      unsigned short zb = f2bf(z);
      A0p[m * 328 + j] = zb;
      a.A0[(size_t)R * 320 + j] = zb;
      a.A1[(size_t)R * 288 + j] = zb;
      a.A2[(size_t)R * 288 + j] = zb;
    }
  }
  __syncthreads();

  // ---- phase C: g0 (A from LDS A0p, W=g0t register ring) ----
  const unsigned short* wlC = a.g0t + (size_t)cl * 320 + q * 8;
  bf16x8 ring2[8];
#pragma unroll
  for (int g = 0; g < 8; g++) ring2[g] = *(const bf16x8*)(wlC + g * 32);
  f32x4 accC = {0.f, 0.f, 0.f, 0.f};
#pragma unroll
  for (int g = 0; g < 10; g++) {
    bf16x8 av = *(const bf16x8*)(A0p + l16 * 328 + g * 32 + q * 8);
    accC = __builtin_amdgcn_mfma_f32_16x16x32_bf16(av, ring2[g % 8], accC, 0, 0, 0);
    if (g + 8 < 10) ring2[g % 8] = *(const bf16x8*)(wlC + (g + 8) * 32);
  }
  {
    float bc = a.g0b[cl];
#pragma unroll
    for (int r = 0; r < 4; r++)
      gaB[(q * 4 + r) * 72 + cl] = f2bf(elu_f(accC[r] + bc));
  }
  __syncthreads();

  // ---- phase D: g1 ----
  f32x4 accD = {0.f, 0.f, 0.f, 0.f};
#pragma unroll
  for (int tau = 0; tau < 2; tau++) {
    bf16x8 av = *(const bf16x8*)(gaB + l16 * 72 + tau * 32 + q * 8);
    bf16x8 bv = *(const bf16x8*)(g1B + cl * 72 + tau * 32 + q * 8);
    accD = __builtin_amdgcn_mfma_f32_16x16x32_bf16(av, bv, accD, 0, 0, 0);
  }
  {
    float bc = a.g1b[cl];
#pragma unroll
    for (int r = 0; r < 4; r++)
      gB[(q * 4 + r) * 65 + cl] = elu_f(accD[r] + bc);
  }
  __syncthreads();

  // ---- phase E: g2 logits + softmax -> cf ----
  if (tid < 128) {
    int r = tid >> 3, e = tid & 7;
    float d = a.g2b[e];
#pragma unroll 8
    for (int k = 0; k < 64; k++) d = fmaf(gB[r * 65 + k], g2wT[k * 8 + e], d);
    lg[r * 8 + e] = d;
  }
  __syncthreads();
  if (tid < 16) {
    float mx = lg[tid * 8];
#pragma unroll
    for (int e2 = 1; e2 < 8; e2++) mx = fmaxf(mx, lg[tid * 8 + e2]);
    float s = 0.f, ex[8];
#pragma unroll
    for (int e2 = 0; e2 < 8; e2++) { ex[e2] = expf(lg[tid * 8 + e2] - mx); s += ex[e2]; }
    float inv = 1.f / s;
#pragma unroll
    for (int e2 = 0; e2 < 8; e2++) a.cf[(size_t)(m0 + tid) * 8 + e2] = ex[e2] * inv;
  }
}

// =====================================================================
extern "C" void kernel_launch(void* const* d_in, const int* in_sizes, int n_in,
                              void* d_out, int out_size, void* d_ws, size_t ws_size,
                              hipStream_t stream) {
  (void)in_sizes; (void)n_in; (void)out_size; (void)ws_size;
  float* out = (float*)d_out;
  float* ws = (float*)d_ws;

  MegaArgs a;
  a.x    = (const float*)d_in[0];
  a.c    = (const float*)d_in[1];
  a.fc1w = (const float*)d_in[2];  a.fc1b = (const float*)d_in[3];
  a.fc2w = (const float*)d_in[4];  a.fc2b = (const float*)d_in[5];
  a.muw  = (const float*)d_in[6];  a.mub  = (const float*)d_in[7];
  a.lvw  = (const float*)d_in[8];  a.lvb  = (const float*)d_in[9];
  a.g0w  = (const float*)d_in[10]; a.g0b  = (const float*)d_in[11];
  a.g1w  = (const float*)d_in[12]; a.g1b  = (const float*)d_in[13];
  a.g2w  = (const float*)d_in[14]; a.g2b  = (const float*)d_in[15];
  a.w0   = (const float*)d_in[16]; a.b0   = (const float*)d_in[17];
  a.w1   = (const float*)d_in[18]; a.b1   = (const float*)d_in[19];
  a.w2   = (const float*)d_in[20]; a.b2   = (const float*)d_in[21];

  a.outY  = out;
  a.outMu = out + 2048 * 267;
  a.outLv = a.outMu + 2048 * 32;

  a.Ax   = (unsigned short*)(ws);
  a.Axh  = (unsigned short*)(ws + 557056);
  a.Axh2 = (unsigned short*)(ws + 1114112);
  a.A0   = (unsigned short*)(ws + 1671168);
  a.A1   = (unsigned short*)(ws + 1998848);
  a.A2   = (unsigned short*)(ws + 2293760);
  a.fc1t = (unsigned short*)(ws + 2588672);
  a.fc2t = (unsigned short*)(ws + 2658304);
  a.mlvt = (unsigned short*)(ws + 2727936);
  a.g0t  = (unsigned short*)(ws + 2745344);
  a.g1t  = (unsigned short*)(ws + 2755584);
  a.w0b  = (unsigned short*)(ws + 2757632);
  a.w1b  = (unsigned short*)(ws + 3085312);
  a.w2b  = (unsigned short*)(ws + 3380224);
  a.cf   = ws + 3687808;

  dim3 blkP(256), blkG(128);
  k_prep<<<1673, blkP, 0, stream>>>(a);
  pipe16<17, 1, 12, true, false><<<dim3(64, 16), blkG, 0, stream>>>(
      a.Ax, a.fc1t, 256, a.fc1b, nullptr, a.Axh, 544, 267, nullptr);
  pipe16<17, 1, 12, true, false><<<dim3(64, 16), blkG, 0, stream>>>(
      a.Axh, a.fc2t, 256, a.fc2b, nullptr, a.Axh2, 544, 267, nullptr);
  k_mulv_gate<<<128, blkP, 0, stream>>>(a);
  pipe16<10, 8, 16, true, false><<<dim3(64, 16), blkG, 0, stream>>>(
      a.A0, a.w0b, 256, a.b0, a.cf, a.A1, 288, 32, nullptr);
  pipe16<9, 8, 16, true, false><<<dim3(64, 16), blkG, 0, stream>>>(
      a.A1, a.w1b, 256, a.b1, a.cf, a.A2, 288, 32, nullptr);
  pipe16<9, 8, 16, false, true><<<dim3(64, 17), blkG, 0, stream>>>(
      a.A2, a.w2b, 267, a.b2, a.cf, nullptr, 0, 0, a.outY);
}